// Round 18
// baseline (480.360 us; speedup 1.0000x reference)
//
#include <hip/hip_runtime.h>
#include <hip/hip_bf16.h>
#include <cstdint>

#define T_TOK 2048
#define HD 2048
#define ID 1408
#define NE 16
#define TOPK 6

#define BM 256      // gemm1 m-tile
#define BM2 128     // gemm2 m-tile
#define BN 64
#define BK 64
#define NT1 22      // ID/BN   (gemm1 n-tiles)
#define NT2 32      // HD/BN   (gemm2 n-tiles)
#define GM2 112     // worst-case sum of ceil(cnt_e/BM2) = 12288/128 + 16

typedef __bf16 bf16x8 __attribute__((ext_vector_type(8)));
typedef float f32x4 __attribute__((ext_vector_type(4)));

typedef const __attribute__((address_space(1))) void* gas1_t;
typedef __attribute__((address_space(3))) void* las3_t;
#define GLDS16(g, l) __builtin_amdgcn_global_load_lds((gas1_t)(g), (las3_t)(l), 16, 0, 0)

// --- routing: combine + lists fused ------------------------------------

__global__ void k_route(const int* __restrict__ idx, const float* __restrict__ w,
                        int* __restrict__ counts, int* __restrict__ tok,
                        float* __restrict__ wts) {
    int t = blockIdx.x * blockDim.x + threadIdx.x;
    if (t >= T_TOK) return;
    int ie[TOPK];
    float fw[TOPK];
#pragma unroll
    for (int k = 0; k < TOPK; k++) { ie[k] = idx[t * TOPK + k]; fw[k] = w[t * TOPK + k]; }
#pragma unroll
    for (int e = 0; e < NE; e++) {
        float s = 0.f;
#pragma unroll
        for (int k = 0; k < TOPK; k++) if (ie[k] == e) s += fw[k];
        if (s != 0.f) {
            int p = atomicAdd(&counts[e], 1);
            tok[e * T_TOK + p] = t;
            wts[e * T_TOK + p] = s;
        }
    }
}

__global__ void k_cvt(const float* __restrict__ x, __bf16* __restrict__ xb) {
    int i = (blockIdx.x * 256 + threadIdx.x) * 8;
    float4 a = *(const float4*)(x + i);
    float4 b = *(const float4*)(x + i + 4);
    bf16x8 o;
    o[0] = (__bf16)a.x; o[1] = (__bf16)a.y; o[2] = (__bf16)a.z; o[3] = (__bf16)a.w;
    o[4] = (__bf16)b.x; o[5] = (__bf16)b.y; o[6] = (__bf16)b.z; o[7] = (__bf16)b.w;
    *(bf16x8*)(xb + i) = o;
}

// --- LDS helpers (128-byte rows, BK=64) ---------------------------------

__device__ __forceinline__ int swz(int row, int cb) {
    return row * 128 + (cb ^ ((row & 7) << 4));
}

__device__ __forceinline__ bf16x8 ldfrag(const __bf16* base, int row, int cb) {
    return *(const bf16x8*)((const char*)base + swz(row, cb));
}

// stage 8 fp32 -> 8 bf16 into LDS (one swizzled 16B store)
__device__ __forceinline__ void stage8(const float* __restrict__ src, char* lds,
                                       int row, int cb) {
    float4 f0 = ((const float4*)src)[0];
    float4 f1 = ((const float4*)src)[1];
    bf16x8 o;
    o[0] = (__bf16)f0.x; o[1] = (__bf16)f0.y; o[2] = (__bf16)f0.z; o[3] = (__bf16)f0.w;
    o[4] = (__bf16)f1.x; o[5] = (__bf16)f1.y; o[6] = (__bf16)f1.z; o[7] = (__bf16)f1.w;
    *(bf16x8*)(lds + swz(row, cb)) = o;
}

// Decode a live work item: e-major, m fastest within e; nm_e = ceil(cnt>>sh).
__device__ __forceinline__ bool decode_item(const int* cnts, int it, int ntn, int sh,
                                            int& e, int& m, int& n, int& cnt) {
    int r = it;
#pragma unroll
    for (int ee = 0; ee < NE; ee++) {
        int c = cnts[ee];
        int nm = (c + (1 << sh) - 1) >> sh;
        int tot = nm * ntn;
        if (r < tot) { e = ee; m = r % nm; n = r / nm; cnt = c; return true; }
        r -= tot;
    }
    return false;
}

// --- GEMM1: act = silu(X@Gg^T) * (X@Gu^T)  ------------------------------
// R16 exactly: persistent blocks + atomic cursor; plain 2-sync K-loop.

__global__ __launch_bounds__(512, 4) void k_gemm1(
    const __bf16* __restrict__ Xb, const float* __restrict__ gup,
    const int* __restrict__ counts, const int* __restrict__ tok,
    __bf16* __restrict__ act, int* __restrict__ cursor) {
    __shared__ __align__(16) __bf16 sA[BM * BK];
    __shared__ __align__(16) __bf16 sBg[BN * BK];
    __shared__ __align__(16) __bf16 sBu[BN * BK];
    __shared__ int s_it;

    int tid = threadIdx.x;
    int lane = tid & 63;
    int wid = tid >> 6;
    int wm = wid >> 1, wn = wid & 1;           // 4x2 waves over 256x64
    int l15 = lane & 15, lh = lane >> 4;
    int csw = ((lane & 7) ^ ((lane >> 3) & 7)) * 8;
    int br = tid >> 3, bc = tid & 7;

    int cnts[NE];
#pragma unroll
    for (int ee = 0; ee < NE; ee++) cnts[ee] = counts[ee];

    while (true) {
        if (tid == 0) s_it = atomicAdd(cursor, 1);
        __syncthreads();
        int e, m, n, cnt;
        if (!decode_item(cnts, s_it, NT1, 8, e, m, n, cnt)) break;
        int m0 = m * BM;
        int n0 = n * BN;

        const __bf16* pA[4];
#pragma unroll
        for (int j = 0; j < 4; j++) {
            int r = 32 * wid + 8 * j + (lane >> 3);
            int g = m0 + r;
            if (g >= cnt) g = cnt - 1;
            pA[j] = Xb + (size_t)tok[e * T_TOK + g] * HD + csw;
        }
        const float* gbase = gup + (size_t)e * (2 * ID) * HD;
        const float* bgSrc = gbase + (size_t)(n0 + br) * HD + bc * 8;
        const float* buSrc = gbase + (size_t)(ID + n0 + br) * HD + bc * 8;

        f32x4 accg[4][2] = {};
        f32x4 accu[4][2] = {};

        for (int k0 = 0; k0 < HD; k0 += BK) {
            __syncthreads();
#pragma unroll
            for (int j = 0; j < 4; j++)
                GLDS16(pA[j] + k0, &sA[(32 * wid + 8 * j) * BK]);
            stage8(bgSrc + k0, (char*)sBg, br, bc * 16);
            stage8(buSrc + k0, (char*)sBu, br, bc * 16);
            __syncthreads();
#pragma unroll
            for (int kk = 0; kk < 2; kk++) {
                int cb = kk * 64 + lh * 16;
                bf16x8 a[4];
#pragma unroll
                for (int fm = 0; fm < 4; fm++)
                    a[fm] = ldfrag(sA, wm * 64 + fm * 16 + l15, cb);
#pragma unroll
                for (int fn = 0; fn < 2; fn++) {
                    bf16x8 bg = ldfrag(sBg, wn * 32 + fn * 16 + l15, cb);
                    bf16x8 bu = ldfrag(sBu, wn * 32 + fn * 16 + l15, cb);
#pragma unroll
                    for (int fm = 0; fm < 4; fm++) {
                        accg[fm][fn] = __builtin_amdgcn_mfma_f32_16x16x32_bf16(a[fm], bg, accg[fm][fn], 0, 0, 0);
                        accu[fm][fn] = __builtin_amdgcn_mfma_f32_16x16x32_bf16(a[fm], bu, accu[fm][fn], 0, 0, 0);
                    }
                }
            }
        }

        // epilogue: silu(gate)*up -> act (bf16)
#pragma unroll
        for (int fm = 0; fm < 4; fm++) {
#pragma unroll
            for (int fn = 0; fn < 2; fn++) {
#pragma unroll
                for (int j = 0; j < 4; j++) {
                    int mloc = wm * 64 + fm * 16 + lh * 4 + j;
                    int g = m0 + mloc;
                    if (g < cnt) {
                        float gv = accg[fm][fn][j];
                        float uv = accu[fm][fn][j];
                        float sv = gv * (1.0f / (1.0f + __expf(-gv)));
                        int nn = n0 + wn * 32 + fn * 16 + l15;
                        act[((size_t)e * T_TOK + g) * ID + nn] = (__bf16)(sv * uv);
                    }
                }
            }
        }
    }
}

// --- GEMM2: out[tok] += (act @ Dn^T) * wt  (fp32 atomic scatter) --------
// BM2=128, 256 threads, LDS 24KB -> 6 blocks/CU: R9's concurrency lever
// applied where bytes stay L3-absorbed. Same 2-sync K-loop.

__global__ __launch_bounds__(256, 6) void k_gemm2(
    const __bf16* __restrict__ act, const float* __restrict__ dn,
    const int* __restrict__ counts, const int* __restrict__ tok,
    const float* __restrict__ wts, float* __restrict__ out) {
    __shared__ __align__(16) __bf16 sA[BM2 * BK];   // 16KB
    __shared__ __align__(16) __bf16 sB[BN * BK];    // 8KB

    int e, m, n, cnt;
    {
        int cnts[NE];
#pragma unroll
        for (int ee = 0; ee < NE; ee++) cnts[ee] = counts[ee];
        if (!decode_item(cnts, blockIdx.x, NT2, 7, e, m, n, cnt)) return;
    }
    int m0 = m * BM2;
    int n0 = n * BN;

    int tid = threadIdx.x;
    int lane = tid & 63;
    int wid = tid >> 6;                // 4 waves
    int wm = wid >> 1, wn = wid & 1;   // 2x2 over 128x64 (wave 64x32)
    int l15 = lane & 15, lh = lane >> 4;
    int csw = ((lane & 7) ^ ((lane >> 3) & 7)) * 8;
    int br = tid >> 2, bc = tid & 3;   // 64 rows x 4 chunks of 16 floats

    const __bf16* pA[4];
#pragma unroll
    for (int j = 0; j < 4; j++) {
        int r = 32 * wid + 8 * j + (lane >> 3);
        int g = m0 + r;
        if (g >= cnt) g = cnt - 1;
        pA[j] = act + ((size_t)e * T_TOK + g) * ID + csw;
    }
    const float* bSrc = dn + (size_t)e * HD * ID + (size_t)(n0 + br) * ID + bc * 16;

    f32x4 acc[4][2] = {};

    for (int k0 = 0; k0 < ID; k0 += BK) {
        __syncthreads();
#pragma unroll
        for (int j = 0; j < 4; j++)
            GLDS16(pA[j] + k0, &sA[(32 * wid + 8 * j) * BK]);
        stage8(bSrc + k0, (char*)sB, br, bc * 32);
        stage8(bSrc + k0 + 8, (char*)sB, br, bc * 32 + 16);
        __syncthreads();
#pragma unroll
        for (int kk = 0; kk < 2; kk++) {
            int cb = kk * 64 + lh * 16;
            bf16x8 a[4];
#pragma unroll
            for (int fm = 0; fm < 4; fm++)
                a[fm] = ldfrag(sA, wm * 64 + fm * 16 + l15, cb);
#pragma unroll
            for (int fn = 0; fn < 2; fn++) {
                bf16x8 b = ldfrag(sB, wn * 32 + fn * 16 + l15, cb);
#pragma unroll
                for (int fm = 0; fm < 4; fm++)
                    acc[fm][fn] = __builtin_amdgcn_mfma_f32_16x16x32_bf16(a[fm], b, acc[fm][fn], 0, 0, 0);
            }
        }
    }

    // epilogue: tok/wts direct from global (L2-hot)
#pragma unroll
    for (int fm = 0; fm < 4; fm++) {
#pragma unroll
        for (int j = 0; j < 4; j++) {
            int mloc = wm * 64 + fm * 16 + lh * 4 + j;
            int g = m0 + mloc;
            if (g < cnt) {
                int t = tok[e * T_TOK + g];
                float w = wts[e * T_TOK + g];
#pragma unroll
                for (int fn = 0; fn < 2; fn++) {
                    int nn = n0 + wn * 32 + fn * 16 + l15;
                    atomicAdd(&out[(size_t)t * HD + nn], acc[fm][fn][j] * w);
                }
            }
        }
    }
}

// --- launch --------------------------------------------------------------

extern "C" void kernel_launch(void* const* d_in, const int* in_sizes, int n_in,
                              void* d_out, int out_size, void* d_ws, size_t ws_size,
                              hipStream_t stream) {
    const float* hs = (const float*)d_in[0];
    const int* tki = (const int*)d_in[1];
    const float* tkw = (const float*)d_in[2];
    const float* gup = (const float*)d_in[3];
    const float* dnp = (const float*)d_in[4];
    float* out = (float*)d_out;

    char* p = (char*)d_ws;
    int* counts = (int*)p;      p += 256;
    int* cursors = (int*)p;     p += 256;       // [0]=gemm1
    int* tok = (int*)p;         p += (size_t)NE * T_TOK * 4;
    float* wts = (float*)p;     p += (size_t)NE * T_TOK * 4;
    __bf16* Xb = (__bf16*)p;    p += (size_t)T_TOK * HD * 2;
    __bf16* act = (__bf16*)p;   // NE*T_TOK*ID*2 = 92MB

    hipMemsetAsync(counts, 0, 512, stream);     // counts + cursors
    hipMemsetAsync(d_out, 0, (size_t)T_TOK * HD * 4, stream);
    k_route<<<T_TOK / 256, 256, 0, stream>>>(tki, tkw, counts, tok, wts);
    k_cvt<<<(T_TOK * HD / 8) / 256, 256, 0, stream>>>(hs, Xb);
    k_gemm1<<<dim3(768), 512, 0, stream>>>(Xb, gup, counts, tok, act, &cursors[0]);
    k_gemm2<<<dim3(GM2 * NT2), 256, 0, stream>>>(act, dnp, counts, tok, wts, out);
}

// Round 19
// 437.857 us; speedup vs baseline: 1.0971x; 1.0971x over previous
//
#include <hip/hip_runtime.h>
#include <hip/hip_bf16.h>
#include <cstdint>

#define T_TOK 2048
#define HD 2048
#define ID 1408
#define NE 16
#define TOPK 6

#define BM 256
#define BN 64
#define BK 64
#define NT1 22   // ID/BN   (gemm1 n-tiles)
#define NT2 32   // HD/BN   (gemm2 n-tiles)
#define GMAX 64  // worst-case sum of ceil(cnt_e/BM)

typedef __bf16 bf16x8 __attribute__((ext_vector_type(8)));
typedef float f32x4 __attribute__((ext_vector_type(4)));

typedef const __attribute__((address_space(1))) void* gas1_t;
typedef __attribute__((address_space(3))) void* las3_t;
#define GLDS16(g, l) __builtin_amdgcn_global_load_lds((gas1_t)(g), (las3_t)(l), 16, 0, 0)

// --- routing: combine + lists fused ------------------------------------

__global__ void k_route(const int* __restrict__ idx, const float* __restrict__ w,
                        int* __restrict__ counts, int* __restrict__ tok,
                        float* __restrict__ wts) {
    int t = blockIdx.x * blockDim.x + threadIdx.x;
    if (t >= T_TOK) return;
    int ie[TOPK];
    float fw[TOPK];
#pragma unroll
    for (int k = 0; k < TOPK; k++) { ie[k] = idx[t * TOPK + k]; fw[k] = w[t * TOPK + k]; }
#pragma unroll
    for (int e = 0; e < NE; e++) {
        float s = 0.f;
#pragma unroll
        for (int k = 0; k < TOPK; k++) if (ie[k] == e) s += fw[k];
        if (s != 0.f) {
            int p = atomicAdd(&counts[e], 1);
            tok[e * T_TOK + p] = t;
            wts[e * T_TOK + p] = s;
        }
    }
}

__global__ void k_cvt(const float* __restrict__ x, __bf16* __restrict__ xb) {
    int i = (blockIdx.x * 256 + threadIdx.x) * 8;
    float4 a = *(const float4*)(x + i);
    float4 b = *(const float4*)(x + i + 4);
    bf16x8 o;
    o[0] = (__bf16)a.x; o[1] = (__bf16)a.y; o[2] = (__bf16)a.z; o[3] = (__bf16)a.w;
    o[4] = (__bf16)b.x; o[5] = (__bf16)b.y; o[6] = (__bf16)b.z; o[7] = (__bf16)b.w;
    *(bf16x8*)(xb + i) = o;
}

// --- LDS helpers (128-byte rows, BK=64) ---------------------------------

__device__ __forceinline__ int swz(int row, int cb) {
    return row * 128 + (cb ^ ((row & 7) << 4));
}

__device__ __forceinline__ bf16x8 ldfrag(const __bf16* base, int row, int cb) {
    return *(const bf16x8*)((const char*)base + swz(row, cb));
}

// stage 8 fp32 -> 8 bf16 into LDS (one swizzled 16B store)
__device__ __forceinline__ void stage8(const float* __restrict__ src, char* lds,
                                       int row, int cb) {
    float4 f0 = ((const float4*)src)[0];
    float4 f1 = ((const float4*)src)[1];
    bf16x8 o;
    o[0] = (__bf16)f0.x; o[1] = (__bf16)f0.y; o[2] = (__bf16)f0.z; o[3] = (__bf16)f0.w;
    o[4] = (__bf16)f1.x; o[5] = (__bf16)f1.y; o[6] = (__bf16)f1.z; o[7] = (__bf16)f1.w;
    *(bf16x8*)(lds + swz(row, cb)) = o;
}

// Decode a live work item: e-major, m fastest within e; nm_e = ceil(cnt/BM).
__device__ __forceinline__ bool decode_item(const int* cnts, int it, int ntn,
                                            int& e, int& m, int& n, int& cnt) {
    int r = it;
#pragma unroll
    for (int ee = 0; ee < NE; ee++) {
        int c = cnts[ee];
        int nm = (c + BM - 1) >> 8;
        int tot = nm * ntn;
        if (r < tot) { e = ee; m = r % nm; n = r / nm; cnt = c; return true; }
        r -= tot;
    }
    return false;
}

// --- GEMM1: act = silu(X@Gg^T) * (X@Gu^T)  ------------------------------
// R8 exactly: persistent blocks + atomic cursor; plain 2-sync K-loop.

__global__ __launch_bounds__(512, 4) void k_gemm1(
    const __bf16* __restrict__ Xb, const float* __restrict__ gup,
    const int* __restrict__ counts, const int* __restrict__ tok,
    __bf16* __restrict__ act, int* __restrict__ cursor) {
    __shared__ __align__(16) __bf16 sA[BM * BK];
    __shared__ __align__(16) __bf16 sBg[BN * BK];
    __shared__ __align__(16) __bf16 sBu[BN * BK];
    __shared__ int s_it;

    int tid = threadIdx.x;
    int lane = tid & 63;
    int wid = tid >> 6;
    int wm = wid >> 1, wn = wid & 1;           // 4x2 waves over 256x64
    int l15 = lane & 15, lh = lane >> 4;
    int csw = ((lane & 7) ^ ((lane >> 3) & 7)) * 8;
    int br = tid >> 3, bc = tid & 7;

    int cnts[NE];
#pragma unroll
    for (int ee = 0; ee < NE; ee++) cnts[ee] = counts[ee];

    while (true) {
        if (tid == 0) s_it = atomicAdd(cursor, 1);
        __syncthreads();
        int e, m, n, cnt;
        if (!decode_item(cnts, s_it, NT1, e, m, n, cnt)) break;
        int m0 = m * BM;
        int n0 = n * BN;

        const __bf16* pA[4];
#pragma unroll
        for (int j = 0; j < 4; j++) {
            int r = 32 * wid + 8 * j + (lane >> 3);
            int g = m0 + r;
            if (g >= cnt) g = cnt - 1;
            pA[j] = Xb + (size_t)tok[e * T_TOK + g] * HD + csw;
        }
        const float* gbase = gup + (size_t)e * (2 * ID) * HD;
        const float* bgSrc = gbase + (size_t)(n0 + br) * HD + bc * 8;
        const float* buSrc = gbase + (size_t)(ID + n0 + br) * HD + bc * 8;

        f32x4 accg[4][2] = {};
        f32x4 accu[4][2] = {};

        for (int k0 = 0; k0 < HD; k0 += BK) {
            __syncthreads();
#pragma unroll
            for (int j = 0; j < 4; j++)
                GLDS16(pA[j] + k0, &sA[(32 * wid + 8 * j) * BK]);
            stage8(bgSrc + k0, (char*)sBg, br, bc * 16);
            stage8(buSrc + k0, (char*)sBu, br, bc * 16);
            __syncthreads();
#pragma unroll
            for (int kk = 0; kk < 2; kk++) {
                int cb = kk * 64 + lh * 16;
                bf16x8 a[4];
#pragma unroll
                for (int fm = 0; fm < 4; fm++)
                    a[fm] = ldfrag(sA, wm * 64 + fm * 16 + l15, cb);
#pragma unroll
                for (int fn = 0; fn < 2; fn++) {
                    bf16x8 bg = ldfrag(sBg, wn * 32 + fn * 16 + l15, cb);
                    bf16x8 bu = ldfrag(sBu, wn * 32 + fn * 16 + l15, cb);
#pragma unroll
                    for (int fm = 0; fm < 4; fm++) {
                        accg[fm][fn] = __builtin_amdgcn_mfma_f32_16x16x32_bf16(a[fm], bg, accg[fm][fn], 0, 0, 0);
                        accu[fm][fn] = __builtin_amdgcn_mfma_f32_16x16x32_bf16(a[fm], bu, accu[fm][fn], 0, 0, 0);
                    }
                }
            }
        }

        // epilogue: silu(gate)*up -> act (bf16)
#pragma unroll
        for (int fm = 0; fm < 4; fm++) {
#pragma unroll
            for (int fn = 0; fn < 2; fn++) {
#pragma unroll
                for (int j = 0; j < 4; j++) {
                    int mloc = wm * 64 + fm * 16 + lh * 4 + j;
                    int g = m0 + mloc;
                    if (g < cnt) {
                        float gv = accg[fm][fn][j];
                        float uv = accu[fm][fn][j];
                        float sv = gv * (1.0f / (1.0f + __expf(-gv)));
                        int nn = n0 + wn * 32 + fn * 16 + l15;
                        act[((size_t)e * T_TOK + g) * ID + nn] = (__bf16)(sv * uv);
                    }
                }
            }
        }
    }
}

// --- GEMM2: out[tok] += (act @ Dn^T) * wt  (fp32 atomic scatter) --------
// Static decode grid, no tok/wts LDS staging -> LDS exactly 40960B ->
// 4 blocks/CU; epilogue reads tok/wts directly from global (L2-hot).

__global__ __launch_bounds__(512, 4) void k_gemm2(
    const __bf16* __restrict__ act, const float* __restrict__ dn,
    const int* __restrict__ counts, const int* __restrict__ tok,
    const float* __restrict__ wts, float* __restrict__ out) {
    __shared__ __align__(16) __bf16 sA[BM * BK];   // 32KB
    __shared__ __align__(16) __bf16 sB[BN * BK];   // 8KB

    int e, m, n, cnt;
    {
        int cnts[NE];
#pragma unroll
        for (int ee = 0; ee < NE; ee++) cnts[ee] = counts[ee];
        if (!decode_item(cnts, blockIdx.x, NT2, e, m, n, cnt)) return;
    }
    int m0 = m * BM;
    int n0 = n * BN;

    int tid = threadIdx.x;
    int lane = tid & 63;
    int wid = tid >> 6;
    int wm = wid >> 1, wn = wid & 1;
    int l15 = lane & 15, lh = lane >> 4;
    int csw = ((lane & 7) ^ ((lane >> 3) & 7)) * 8;
    int br = tid >> 3, bc = tid & 7;

    const __bf16* pA[4];
#pragma unroll
    for (int j = 0; j < 4; j++) {
        int r = 32 * wid + 8 * j + (lane >> 3);
        int g = m0 + r;
        if (g >= cnt) g = cnt - 1;
        pA[j] = act + ((size_t)e * T_TOK + g) * ID + csw;
    }
    const float* bSrc = dn + (size_t)e * HD * ID + (size_t)(n0 + br) * ID + bc * 8;

    f32x4 acc[4][2] = {};

    for (int k0 = 0; k0 < ID; k0 += BK) {
        __syncthreads();
#pragma unroll
        for (int j = 0; j < 4; j++)
            GLDS16(pA[j] + k0, &sA[(32 * wid + 8 * j) * BK]);
        stage8(bSrc + k0, (char*)sB, br, bc * 16);
        __syncthreads();
#pragma unroll
        for (int kk = 0; kk < 2; kk++) {
            int cb = kk * 64 + lh * 16;
            bf16x8 a[4];
#pragma unroll
            for (int fm = 0; fm < 4; fm++)
                a[fm] = ldfrag(sA, wm * 64 + fm * 16 + l15, cb);
#pragma unroll
            for (int fn = 0; fn < 2; fn++) {
                bf16x8 b = ldfrag(sB, wn * 32 + fn * 16 + l15, cb);
#pragma unroll
                for (int fm = 0; fm < 4; fm++)
                    acc[fm][fn] = __builtin_amdgcn_mfma_f32_16x16x32_bf16(a[fm], b, acc[fm][fn], 0, 0, 0);
            }
        }
    }

    // epilogue: tok/wts direct from global (L2-hot, 16 rows/thread)
#pragma unroll
    for (int fm = 0; fm < 4; fm++) {
#pragma unroll
        for (int j = 0; j < 4; j++) {
            int mloc = wm * 64 + fm * 16 + lh * 4 + j;
            int g = m0 + mloc;
            if (g < cnt) {
                int t = tok[e * T_TOK + g];
                float w = wts[e * T_TOK + g];
#pragma unroll
                for (int fn = 0; fn < 2; fn++) {
                    int nn = n0 + wn * 32 + fn * 16 + l15;
                    atomicAdd(&out[(size_t)t * HD + nn], acc[fm][fn][j] * w);
                }
            }
        }
    }
}

// --- launch --------------------------------------------------------------

extern "C" void kernel_launch(void* const* d_in, const int* in_sizes, int n_in,
                              void* d_out, int out_size, void* d_ws, size_t ws_size,
                              hipStream_t stream) {
    const float* hs = (const float*)d_in[0];
    const int* tki = (const int*)d_in[1];
    const float* tkw = (const float*)d_in[2];
    const float* gup = (const float*)d_in[3];
    const float* dnp = (const float*)d_in[4];
    float* out = (float*)d_out;

    char* p = (char*)d_ws;
    int* counts = (int*)p;      p += 256;
    int* cursors = (int*)p;     p += 256;       // [0]=gemm1
    int* tok = (int*)p;         p += (size_t)NE * T_TOK * 4;
    float* wts = (float*)p;     p += (size_t)NE * T_TOK * 4;
    __bf16* Xb = (__bf16*)p;    p += (size_t)T_TOK * HD * 2;
    __bf16* act = (__bf16*)p;   // NE*T_TOK*ID*2 = 92MB

    hipMemsetAsync(counts, 0, 512, stream);     // counts + cursors
    hipMemsetAsync(d_out, 0, (size_t)T_TOK * HD * 4, stream);
    k_route<<<T_TOK / 256, 256, 0, stream>>>(tki, tkw, counts, tok, wts);
    k_cvt<<<(T_TOK * HD / 8) / 256, 256, 0, stream>>>(hs, Xb);
    k_gemm1<<<dim3(768), 512, 0, stream>>>(Xb, gup, counts, tok, act, &cursors[0]);
    k_gemm2<<<dim3(GMAX * NT2), 512, 0, stream>>>(act, dnp, counts, tok, wts, out);
}